// Round 2
// baseline (10957.286 us; speedup 1.0000x reference)
//
#include <hip/hip_runtime.h>
#include <cmath>

// CapsNet forward, fp32, low-workspace design (ws = 30.7 MB).
//  w2_transpose: (co,ci,ky,kx) -> w2t[(ci*81+ky*9+kx)][co]
//  conv2_fused : per (image, co-half) block; recomputes conv1 32-ch chunks
//                into LDS on the fly; writes xcaps[b][n][d]
//  routing_fused: per (o,b) block; u_hat into registers; 3 routing passes
// ws layout (floats): w2t 5,308,416 | xcaps 2,359,296

// ---------------- w2 transpose ----------------
__global__ __launch_bounds__(256) void w2_transpose(const float* __restrict__ w2,
                                                    float* __restrict__ w2t) {
  __shared__ float tile[64][65];
  const int t = threadIdx.x;
  const int ck0 = blockIdx.x * 64;  // 324 blocks cover 20736
  const int co0 = blockIdx.y * 64;  // 4 blocks cover 256
  const int r0 = t >> 6;            // 0..3
  const int c = t & 63;
#pragma unroll
  for (int rr = 0; rr < 16; ++rr) {
    const int r = rr * 4 + r0;
    tile[r][c] = w2[(size_t)(co0 + r) * 20736 + ck0 + c];
  }
  __syncthreads();
#pragma unroll
  for (int rr = 0; rr < 16; ++rr) {
    const int r = rr * 4 + r0;
    w2t[(size_t)(ck0 + r) * 256 + co0 + c] = tile[c][r];
  }
}

// ---------------- conv2 with fused conv1 ----------------
// grid 512 = (b:256) x (coh:2), blockIdx = b*2+coh. 384 threads.
// Phase A roles: ciA = t&31 (channel in chunk), sub = t>>5 (row group)
// Phase B roles: col = t&63 (co = coh*128+col and +64), oyB = t>>6 (0..5)
__global__ __launch_bounds__(384) void conv2_fused(
    const float* __restrict__ data, const float* __restrict__ w1,
    const float* __restrict__ b1, const float* __restrict__ w2t,
    const float* __restrict__ b2, float* __restrict__ xcaps) {
  const int t = threadIdx.x;
  const int b = blockIdx.x >> 1;
  const int coh = blockIdx.x & 1;
  __shared__ float simg[28 * 32];    // image, rows padded to 32
  __shared__ float w1s[32 * 81];     // conv1 weights for current chunk
  __shared__ float schunk[32 * 400]; // conv1 output chunk (32 ch x 20x20)

  for (int i = t; i < 784; i += 384)
    simg[(i / 28) * 32 + (i % 28)] = data[b * 784 + i];

  const int ciA = t & 31, sub = t >> 5;
  const int col = t & 63, oyB = t >> 6;
  const int co0 = coh * 128 + col;

  double tot[12];
#pragma unroll
  for (int j = 0; j < 12; ++j) tot[j] = 0.0;

  for (int chunk = 0; chunk < 8; ++chunk) {
    __syncthreads();  // prev chunk fully consumed; safe to overwrite LDS
    for (int i = t; i < 2592; i += 384) w1s[i] = w1[chunk * 2592 + i];
    __syncthreads();
    // ---- phase A: conv1 (k9 s1 + bias + relu) for 32 channels ----
    {
      const float bias = b1[chunk * 32 + ciA];
      const float* wrow = &w1s[ciA * 81];
      float* orow = &schunk[ciA * 400];
#pragma unroll
      for (int half = 0; half < 2; ++half) {
        const int r = sub + half * 12;
        if (r < 20) {
          float acc[20];
#pragma unroll
          for (int ox = 0; ox < 20; ++ox) acc[ox] = bias;
#pragma unroll
          for (int ky = 0; ky < 9; ++ky) {
            float rr[28];
#pragma unroll
            for (int q = 0; q < 7; ++q)
              *(float4*)&rr[q * 4] = *(const float4*)&simg[(r + ky) * 32 + q * 4];
#pragma unroll
            for (int kx = 0; kx < 9; ++kx) {
              const float w = wrow[ky * 9 + kx];
#pragma unroll
              for (int ox = 0; ox < 20; ++ox) acc[ox] = fmaf(w, rr[ox + kx], acc[ox]);
            }
          }
#pragma unroll
          for (int q = 0; q < 5; ++q) {
            float4 v;
            v.x = fmaxf(acc[q * 4 + 0], 0.f);
            v.y = fmaxf(acc[q * 4 + 1], 0.f);
            v.z = fmaxf(acc[q * 4 + 2], 0.f);
            v.w = fmaxf(acc[q * 4 + 3], 0.f);
            *(float4*)&orow[r * 20 + q * 4] = v;
          }
        }
      }
    }
    __syncthreads();
    // ---- phase B: conv2 consume (k9 s2), 2 co x 1 row x 6 cols ----
    for (int ci = 0; ci < 32; ++ci) {
      float ca[12];  // per-ci fp32 sub-accumulators (error control)
#pragma unroll
      for (int j = 0; j < 12; ++j) ca[j] = 0.f;
#pragma unroll
      for (int ky = 0; ky < 9; ++ky) {
        float r0[20];
        const float* rp = &schunk[ci * 400 + (2 * oyB + ky) * 20];
#pragma unroll
        for (int q = 0; q < 5; ++q) *(float4*)&r0[q * 4] = *(const float4*)&rp[q * 4];
        const float* wp = w2t + (size_t)((chunk * 32 + ci) * 81 + ky * 9) * 256 + co0;
#pragma unroll
        for (int kx = 0; kx < 9; ++kx) {
          const float wA = wp[kx * 256];
          const float wB = wp[kx * 256 + 64];
#pragma unroll
          for (int ox = 0; ox < 6; ++ox) {
            ca[ox] = fmaf(wA, r0[2 * ox + kx], ca[ox]);
            ca[6 + ox] = fmaf(wB, r0[2 * ox + kx], ca[6 + ox]);
          }
        }
      }
#pragma unroll
      for (int j = 0; j < 12; ++j) tot[j] += (double)ca[j];
    }
  }
  // ---- store xcaps[b][n][d]; n = m*36 + oy*6 + ox, d = co>>5, m = co&31 ----
#pragma unroll
  for (int cc = 0; cc < 2; ++cc) {
    const int co = co0 + cc * 64;
    const int d = co >> 5, m = co & 31;
    const double bias = (double)b2[co];
#pragma unroll
    for (int ox = 0; ox < 6; ++ox) {
      const int n = m * 36 + oyB * 6 + ox;
      xcaps[((size_t)b * 1152 + n) * 8 + d] = (float)(tot[cc * 6 + ox] + bias);
    }
  }
}

// ---------------- fused u_hat + routing: block per (o,b) ----------------
// blockIdx = o*256 + b (o-major: same-o blocks cluster in time -> W o-slice
// stays hot in per-XCD L2). 256 threads = ng(16 groups of 72 n) x k(16).
__global__ __launch_bounds__(256) void routing_fused(const float* __restrict__ xcaps,
                                                     const float* __restrict__ W,
                                                     float* __restrict__ out) {
  const int o = blockIdx.x >> 8;
  const int b = blockIdx.x & 255;
  const int t = threadIdx.x;
  const int k = t & 15, ng = t >> 4;
  __shared__ float xs[1152 * 9];  // x[b] padded stride 8->9 (bank spread)
  __shared__ double redA[256];
  __shared__ double redB[256];
  __shared__ float s_s[16];
  __shared__ float s_sv;
  __shared__ double s_f;

  {
    const float4* src = (const float4*)(xcaps + (size_t)b * 9216);
    for (int idx = t; idx < 2304; idx += 256) {
      float4 v = src[idx];
      const int n = idx >> 1, h = idx & 1;
      float* dst = &xs[n * 9 + h * 4];
      dst[0] = v.x; dst[1] = v.y; dst[2] = v.z; dst[3] = v.w;
    }
  }
  __syncthreads();

  // ---- u_hat for this thread's 72 input capsules, fixed k ----
  const int n0 = ng * 72;
  float u[72];
  const float* wp = W + ((size_t)(n0 * 10 + o) * 16 + k) * 8;
#pragma unroll
  for (int i = 0; i < 72; ++i) {
    const float* wq = wp + (size_t)i * 1280;  // n-stride = 10*16*8
    const float4 wa = *(const float4*)wq;
    const float4 wb = *(const float4*)(wq + 4);
    const float* xp = &xs[(n0 + i) * 9];
    float s = fmaf(wa.x, xp[0], 0.f);
    s = fmaf(wa.y, xp[1], s);
    s = fmaf(wa.z, xp[2], s);
    s = fmaf(wa.w, xp[3], s);
    s = fmaf(wb.x, xp[4], s);
    s = fmaf(wb.y, xp[5], s);
    s = fmaf(wb.z, xp[6], s);
    s = fmaf(wb.w, xp[7], s);
    u[i] = s;
  }

  // ---- pass 1: uniform c = 1/1152 ----
  double S = 0.0;
#pragma unroll
  for (int i = 0; i < 72; ++i) S += (double)u[i];
  redA[t] = S;
  __syncthreads();
  if (t < 16) {
    double tot = 0.0;
#pragma unroll
    for (int g = 0; g < 16; ++g) tot += redA[g * 16 + t];
    s_s[t] = (float)(tot * (double)(1.0f / 1152.0f));
  }
  __syncthreads();
  if (t == 0) {
    double sn = 0.0;
#pragma unroll
    for (int kk = 0; kk < 16; ++kk) sn += (double)s_s[kk] * (double)s_s[kk];
    const double f = sn / ((1.0 + sn) * sqrt(sn));
    double sv = 0.0;
#pragma unroll
    for (int kk = 0; kk < 16; ++kk) sv += (double)s_s[kk] * f;
    s_sv = (float)sv;
  }
  __syncthreads();
  const float sv1 = s_sv;

  // ---- pass 2: logits u*sv1 (per-k softmax over n) ----
  double E = 0.0, EU = 0.0;
#pragma unroll
  for (int i = 0; i < 72; ++i) {
    const float e = expf(u[i] * sv1);
    E += (double)e;
    EU += (double)e * (double)u[i];
  }
  redA[t] = E; redB[t] = EU;
  __syncthreads();
  if (t < 16) {
    double te = 0.0, tu = 0.0;
#pragma unroll
    for (int g = 0; g < 16; ++g) { te += redA[g * 16 + t]; tu += redB[g * 16 + t]; }
    s_s[t] = (float)(tu / te);
  }
  __syncthreads();
  if (t == 0) {
    double sn = 0.0;
#pragma unroll
    for (int kk = 0; kk < 16; ++kk) sn += (double)s_s[kk] * (double)s_s[kk];
    const double f = sn / ((1.0 + sn) * sqrt(sn));
    double sv = 0.0;
#pragma unroll
    for (int kk = 0; kk < 16; ++kk) sv += (double)s_s[kk] * f;
    s_sv = sv1 + (float)sv;
  }
  __syncthreads();
  const float sv12 = s_sv;

  // ---- pass 3: logits u*(sv1+sv2) -> output ----
  E = 0.0; EU = 0.0;
#pragma unroll
  for (int i = 0; i < 72; ++i) {
    const float e = expf(u[i] * sv12);
    E += (double)e;
    EU += (double)e * (double)u[i];
  }
  redA[t] = E; redB[t] = EU;
  __syncthreads();
  if (t < 16) {
    double te = 0.0, tu = 0.0;
#pragma unroll
    for (int g = 0; g < 16; ++g) { te += redA[g * 16 + t]; tu += redB[g * 16 + t]; }
    s_s[t] = (float)(tu / te);
  }
  __syncthreads();
  if (t == 0) {
    double sn = 0.0;
#pragma unroll
    for (int kk = 0; kk < 16; ++kk) sn += (double)s_s[kk] * (double)s_s[kk];
    s_f = sn / ((1.0 + sn) * sqrt(sn));
  }
  __syncthreads();
  if (t < 16) out[b * 160 + o * 16 + t] = (float)((double)s_s[t] * s_f);
}

extern "C" void kernel_launch(void* const* d_in, const int* in_sizes, int n_in,
                              void* d_out, int out_size, void* d_ws, size_t ws_size,
                              hipStream_t stream) {
  const float* data = (const float*)d_in[0];
  const float* w1   = (const float*)d_in[1];
  const float* b1   = (const float*)d_in[2];
  const float* w2   = (const float*)d_in[3];
  const float* b2   = (const float*)d_in[4];
  const float* W    = (const float*)d_in[5];
  float* out = (float*)d_out;

  float* w2t   = (float*)d_ws;          // 5,308,416 floats (21.2 MB)
  float* xcaps = w2t + 5308416;         // 2,359,296 floats ( 9.4 MB)

  w2_transpose<<<dim3(324, 4), 256, 0, stream>>>(w2, w2t);
  conv2_fused<<<512, 384, 0, stream>>>(data, w1, b1, w2t, b2, xcaps);
  routing_fused<<<2560, 256, 0, stream>>>(xcaps, W, out);
}

// Round 3
// 2142.536 us; speedup vs baseline: 5.1142x; 5.1142x over previous
//
#include <hip/hip_runtime.h>
#include <cmath>

// CapsNet forward, fp32, ws = 30.7 MB.
//  w2_transpose: (co,ci,ky,kx) -> w2p[ck][pair-interleaved co] (float2 loads)
//  conv2_fused : grid 1024 = img(256) x coh(2) x oyh(2); block 192 thr
//                = 64 col x 3 oyl; 2 co/thread; 8-ch conv1 chunks recomputed
//                into LDS (13 rows only); writes xcaps[b][n][d]
//  routing_fused: per (o,b) block; u_hat in registers; 3 algebraic passes
// ws layout (floats): w2p 5,308,416 | xcaps 2,359,296

// ---------------- w2 transpose + pair interleave ----------------
// out[ck*256 + (co&128) + (co&63)*2 + ((co>>6)&1)] = w2[co][ck]
__global__ __launch_bounds__(256) void w2_transpose(const float* __restrict__ w2,
                                                    float* __restrict__ w2p) {
  __shared__ float tile[64][65];
  const int t = threadIdx.x;
  const int ck0 = blockIdx.x * 64;  // 324 blocks cover 20736
  const int co0 = blockIdx.y * 64;  // 4 blocks cover 256
  const int r0 = t >> 6;            // 0..3
  const int c = t & 63;
#pragma unroll
  for (int rr = 0; rr < 16; ++rr) {
    const int r = rr * 4 + r0;
    tile[r][c] = w2[(size_t)(co0 + r) * 20736 + ck0 + c];
  }
  __syncthreads();
  const int perm = (co0 & 128) + c * 2 + ((co0 >> 6) & 1);  // perm(co0+c)
#pragma unroll
  for (int rr = 0; rr < 16; ++rr) {
    const int r = rr * 4 + r0;
    w2p[(size_t)(ck0 + r) * 256 + perm] = tile[c][r];
  }
}

// ---------------- conv2 with fused conv1 ----------------
__global__ __launch_bounds__(192) void conv2_fused(
    const float* __restrict__ data, const float* __restrict__ w1,
    const float* __restrict__ b1, const float* __restrict__ w2p,
    const float* __restrict__ b2, float* __restrict__ xcaps) {
  const int t = threadIdx.x;
  const int b = blockIdx.x >> 2;
  const int coh = (blockIdx.x >> 1) & 1;
  const int oyh = blockIdx.x & 1;

  __shared__ float simg[28 * 36];   // image, rows padded to 36 (bank-spread)
  __shared__ float schunk[8 * 260]; // 8 ch x 13 rows x 20 cols

  for (int i = t; i < 784; i += 192)
    simg[(i / 28) * 36 + (i % 28)] = data[b * 784 + i];

  // phase A role: 104 tasks = 8 ch x 13 rows
  const int ciA = t & 7, rA = t >> 3;
  // phase B role
  const int col = t & 63, oyl = t >> 6;  // oyl 0..2
  const int co1 = coh * 128 + col;       // and co2 = co1 + 64

  double tot[12];
#pragma unroll
  for (int j = 0; j < 12; ++j) tot[j] = 0.0;

  for (int chunk = 0; chunk < 32; ++chunk) {
    __syncthreads();  // simg ready (chunk 0) / prev phase B done with schunk
    // ---- phase A: conv1 rows [oyh*6, oyh*6+13) for 8 channels ----
    if (t < 104) {
      const int ch = chunk * 8 + ciA;
      const int r = oyh * 6 + rA;
      const float* wr = w1 + ch * 81;   // L1-hot broadcast stream
      const float bias = b1[ch];
      float acc[20];
#pragma unroll
      for (int ox = 0; ox < 20; ++ox) acc[ox] = bias;
#pragma unroll
      for (int ky = 0; ky < 9; ++ky) {
        float rr[28];
#pragma unroll
        for (int q = 0; q < 7; ++q)
          *(float4*)&rr[q * 4] = *(const float4*)&simg[(r + ky) * 36 + q * 4];
#pragma unroll
        for (int kx = 0; kx < 9; ++kx) {
          const float w = wr[ky * 9 + kx];
#pragma unroll
          for (int ox = 0; ox < 20; ++ox) acc[ox] = fmaf(w, rr[ox + kx], acc[ox]);
        }
      }
      float* orow = &schunk[ciA * 260 + rA * 20];
#pragma unroll
      for (int q = 0; q < 5; ++q) {
        float4 v;
        v.x = fmaxf(acc[q * 4 + 0], 0.f);
        v.y = fmaxf(acc[q * 4 + 1], 0.f);
        v.z = fmaxf(acc[q * 4 + 2], 0.f);
        v.w = fmaxf(acc[q * 4 + 3], 0.f);
        *(float4*)&orow[q * 4] = v;
      }
    }
    __syncthreads();
    // ---- phase B: conv2 consume; 2 co x 1 oy x 6 ox per thread ----
    for (int ci = 0; ci < 8; ++ci) {
      float ca[12];
#pragma unroll
      for (int j = 0; j < 12; ++j) ca[j] = 0.f;
#pragma unroll
      for (int ky = 0; ky < 9; ++ky) {
        float r0[20];
        const float* rp = &schunk[ci * 260 + (2 * oyl + ky) * 20];
#pragma unroll
        for (int q = 0; q < 5; ++q) *(float4*)&r0[q * 4] = *(const float4*)&rp[q * 4];
        const float2* wp = (const float2*)&w2p[(size_t)((chunk * 8 + ci) * 81 + ky * 9) * 256
                                               + coh * 128 + col * 2];
#pragma unroll
        for (int kx = 0; kx < 9; ++kx) {
          const float2 w = wp[kx * 128];  // (co1, co2) weights
#pragma unroll
          for (int ox = 0; ox < 6; ++ox) {
            ca[ox]     = fmaf(w.x, r0[2 * ox + kx], ca[ox]);
            ca[6 + ox] = fmaf(w.y, r0[2 * ox + kx], ca[6 + ox]);
          }
        }
      }
#pragma unroll
      for (int j = 0; j < 12; ++j) tot[j] += (double)ca[j];
    }
  }
  // ---- store xcaps[b][n][d]; n = m*36 + oy*6 + ox, d = co>>5, m = co&31 ----
  const int oy = oyh * 3 + oyl;
#pragma unroll
  for (int cc = 0; cc < 2; ++cc) {
    const int co = co1 + cc * 64;
    const int d = co >> 5, m = co & 31;
    const double bias = (double)b2[co];
#pragma unroll
    for (int ox = 0; ox < 6; ++ox) {
      const int n = m * 36 + oy * 6 + ox;
      xcaps[((size_t)b * 1152 + n) * 8 + d] = (float)(tot[cc * 6 + ox] + bias);
    }
  }
}

// ---------------- fused u_hat + routing: block per (o,b) ----------------
__global__ __launch_bounds__(256) void routing_fused(const float* __restrict__ xcaps,
                                                     const float* __restrict__ W,
                                                     float* __restrict__ out) {
  const int o = blockIdx.x >> 8;
  const int b = blockIdx.x & 255;
  const int t = threadIdx.x;
  const int k = t & 15, ng = t >> 4;
  __shared__ float xs[1152 * 9];  // x[b] padded stride 8->9
  __shared__ double redA[256];
  __shared__ double redB[256];
  __shared__ float s_s[16];
  __shared__ float s_sv;
  __shared__ double s_f;

  {
    const float4* src = (const float4*)(xcaps + (size_t)b * 9216);
    for (int idx = t; idx < 2304; idx += 256) {
      float4 v = src[idx];
      const int n = idx >> 1, h = idx & 1;
      float* dst = &xs[n * 9 + h * 4];
      dst[0] = v.x; dst[1] = v.y; dst[2] = v.z; dst[3] = v.w;
    }
  }
  __syncthreads();

  const int n0 = ng * 72;
  float u[72];
  const float* wp = W + ((size_t)(n0 * 10 + o) * 16 + k) * 8;
#pragma unroll
  for (int i = 0; i < 72; ++i) {
    const float* wq = wp + (size_t)i * 1280;
    const float4 wa = *(const float4*)wq;
    const float4 wb = *(const float4*)(wq + 4);
    const float* xp = &xs[(n0 + i) * 9];
    float s = fmaf(wa.x, xp[0], 0.f);
    s = fmaf(wa.y, xp[1], s);
    s = fmaf(wa.z, xp[2], s);
    s = fmaf(wa.w, xp[3], s);
    s = fmaf(wb.x, xp[4], s);
    s = fmaf(wb.y, xp[5], s);
    s = fmaf(wb.z, xp[6], s);
    s = fmaf(wb.w, xp[7], s);
    u[i] = s;
  }

  // ---- pass 1: uniform c = 1/1152 ----
  double S = 0.0;
#pragma unroll
  for (int i = 0; i < 72; ++i) S += (double)u[i];
  redA[t] = S;
  __syncthreads();
  if (t < 16) {
    double tt = 0.0;
#pragma unroll
    for (int g = 0; g < 16; ++g) tt += redA[g * 16 + t];
    s_s[t] = (float)(tt * (double)(1.0f / 1152.0f));
  }
  __syncthreads();
  if (t == 0) {
    double sn = 0.0;
#pragma unroll
    for (int kk = 0; kk < 16; ++kk) sn += (double)s_s[kk] * (double)s_s[kk];
    const double f = sn / ((1.0 + sn) * sqrt(sn));
    double sv = 0.0;
#pragma unroll
    for (int kk = 0; kk < 16; ++kk) sv += (double)s_s[kk] * f;
    s_sv = (float)sv;
  }
  __syncthreads();
  const float sv1 = s_sv;

  // ---- pass 2: logits u*sv1 ----
  double E = 0.0, EU = 0.0;
#pragma unroll
  for (int i = 0; i < 72; ++i) {
    const float e = expf(u[i] * sv1);
    E += (double)e;
    EU += (double)e * (double)u[i];
  }
  redA[t] = E; redB[t] = EU;
  __syncthreads();
  if (t < 16) {
    double te = 0.0, tu = 0.0;
#pragma unroll
    for (int g = 0; g < 16; ++g) { te += redA[g * 16 + t]; tu += redB[g * 16 + t]; }
    s_s[t] = (float)(tu / te);
  }
  __syncthreads();
  if (t == 0) {
    double sn = 0.0;
#pragma unroll
    for (int kk = 0; kk < 16; ++kk) sn += (double)s_s[kk] * (double)s_s[kk];
    const double f = sn / ((1.0 + sn) * sqrt(sn));
    double sv = 0.0;
#pragma unroll
    for (int kk = 0; kk < 16; ++kk) sv += (double)s_s[kk] * f;
    s_sv = sv1 + (float)sv;
  }
  __syncthreads();
  const float sv12 = s_sv;

  // ---- pass 3 -> output ----
  E = 0.0; EU = 0.0;
#pragma unroll
  for (int i = 0; i < 72; ++i) {
    const float e = expf(u[i] * sv12);
    E += (double)e;
    EU += (double)e * (double)u[i];
  }
  redA[t] = E; redB[t] = EU;
  __syncthreads();
  if (t < 16) {
    double te = 0.0, tu = 0.0;
#pragma unroll
    for (int g = 0; g < 16; ++g) { te += redA[g * 16 + t]; tu += redB[g * 16 + t]; }
    s_s[t] = (float)(tu / te);
  }
  __syncthreads();
  if (t == 0) {
    double sn = 0.0;
#pragma unroll
    for (int kk = 0; kk < 16; ++kk) sn += (double)s_s[kk] * (double)s_s[kk];
    s_f = sn / ((1.0 + sn) * sqrt(sn));
  }
  __syncthreads();
  if (t < 16) out[b * 160 + o * 16 + t] = (float)((double)s_s[t] * s_f);
}

extern "C" void kernel_launch(void* const* d_in, const int* in_sizes, int n_in,
                              void* d_out, int out_size, void* d_ws, size_t ws_size,
                              hipStream_t stream) {
  const float* data = (const float*)d_in[0];
  const float* w1   = (const float*)d_in[1];
  const float* b1   = (const float*)d_in[2];
  const float* w2   = (const float*)d_in[3];
  const float* b2   = (const float*)d_in[4];
  const float* W    = (const float*)d_in[5];
  float* out = (float*)d_out;

  float* w2p   = (float*)d_ws;          // 5,308,416 floats (21.2 MB)
  float* xcaps = w2p + 5308416;         // 2,359,296 floats ( 9.4 MB)

  w2_transpose<<<dim3(324, 4), 256, 0, stream>>>(w2, w2p);
  conv2_fused<<<1024, 192, 0, stream>>>(data, w1, b1, w2p, b2, xcaps);
  routing_fused<<<2560, 256, 0, stream>>>(xcaps, W, out);
}

// Round 4
// 810.662 us; speedup vs baseline: 13.5165x; 2.6429x over previous
//
#include <hip/hip_runtime.h>
#include <hip/hip_bf16.h>
#include <cmath>

// CapsNet forward. conv2 via split-bf16 MFMA (hi/lo 2-term split, 4 cross
// products -> ~fp32 product accuracy), conv1 fused in fp32 on VALU.
//  prep_w2    : w2 (co,ci,9,9) -> whi/wlo[tap][co][ci] bf16 split
//  conv2_mfma : grid 512 = img(256) x coh(2); 256 thr (4 waves).
//               M=36 pos (pad 48, 3 Mtiles), N=128 co (2 Ntiles/wave),
//               K=256 ci in 8 chunks. Phase A: conv1 chunk -> LDS bf16 hi/lo.
//               Phase B: 81 taps x 4-split mfma_f32_16x16x32_bf16.
//  routing_fused: unchanged (passed, absmax 1.9e-6).
// ws (bytes): whi 10,616,832 | wlo 10,616,832 | xcaps 9,437,184  = 30.7 MB

typedef float f32x4 __attribute__((ext_vector_type(4)));
typedef short s16x4 __attribute__((ext_vector_type(4)));
typedef short s16x8 __attribute__((ext_vector_type(8)));

static __device__ __forceinline__ short f2bf(float x) {
  __hip_bfloat16 h = __float2bfloat16(x);
  return *reinterpret_cast<short*>(&h);
}
static __device__ __forceinline__ float bf2f(short s) {
  __hip_bfloat16 h;
  *reinterpret_cast<short*>(&h) = s;
  return __bfloat162float(h);
}

// ---------------- w2 split + transpose ----------------
__global__ __launch_bounds__(256) void prep_w2(const float* __restrict__ w2,
                                               short* __restrict__ whi,
                                               short* __restrict__ wlo) {
  const int co = blockIdx.x;
  const int ci = threadIdx.x;
  const float* src = w2 + ((size_t)co * 256 + ci) * 81;  // contiguous taps
  for (int tap = 0; tap < 81; ++tap) {
    const float x = src[tap];
    const short hi = f2bf(x);
    const short lo = f2bf(x - bf2f(hi));
    const size_t idx = ((size_t)tap * 256 + co) * 256 + ci;  // ci coalesced
    whi[idx] = hi;
    wlo[idx] = lo;
  }
}

// ---------------- conv1 + conv2 via MFMA ----------------
__global__ __launch_bounds__(256) void conv2_mfma(
    const float* __restrict__ data, const float* __restrict__ w1,
    const float* __restrict__ b1, const short* __restrict__ whi,
    const short* __restrict__ wlo, const float* __restrict__ b2,
    float* __restrict__ xcaps) {
  const int t = threadIdx.x;
  const int b = blockIdx.x >> 1;
  const int coh = blockIdx.x & 1;
  const int lane = t & 63;
  const int wv = t >> 6;  // wave 0..3

  __shared__ float simg[28 * 36];   // image rows padded to 36
  __shared__ short c1hi[400 * 36];  // [pos(20x20)][ci-chunk 32, pad 36]
  __shared__ short c1lo[400 * 36];

  for (int i = t; i < 784; i += 256)
    simg[(i / 28) * 36 + (i % 28)] = data[b * 784 + i];

  const int r16 = lane & 15;  // A row / B col / D col
  const int kg = lane >> 4;   // k-group: k = kg*8 + i

  // A-fragment base element offsets for the 3 M-tiles (pad rows clamped)
  int abase[3];
#pragma unroll
  for (int m = 0; m < 3; ++m) {
    int pos = m * 16 + r16;
    if (pos > 35) pos = 35;  // pad rows: read pos 35, discard at store
    const int oy = pos / 6, ox = pos % 6;
    abase[m] = (oy * 2 * 20 + ox * 2) * 36 + kg * 8;
  }
  // B-fragment element offsets within a tap slab (256co x 256ci)
  int boff[2], con[2];
  float bias[2];
#pragma unroll
  for (int j = 0; j < 2; ++j) {
    const int co = coh * 128 + (wv * 2 + j) * 16 + r16;
    con[j] = co;
    boff[j] = co * 256 + kg * 8;
    bias[j] = b2[co];
  }

  const f32x4 vzero = {0.f, 0.f, 0.f, 0.f};
  f32x4 acc[3][2];
#pragma unroll
  for (int m = 0; m < 3; ++m)
#pragma unroll
    for (int j = 0; j < 2; ++j) acc[m][j] = vzero;

  for (int chunk = 0; chunk < 8; ++chunk) {
    __syncthreads();  // simg ready / prev phase B done with c1 buffers
    // ---- phase A: conv1 (k9 s1, bias, relu) for 32 channels, split to LDS
    for (int task = t; task < 640; task += 256) {
      const int ci = task & 31, y = task >> 5;  // y 0..19
      const int ch = chunk * 32 + ci;
      const float* wr = w1 + ch * 81;
      const float bz = b1[ch];
      float a20[20];
#pragma unroll
      for (int ox = 0; ox < 20; ++ox) a20[ox] = bz;
#pragma unroll
      for (int ky = 0; ky < 9; ++ky) {
        float rr[28];
#pragma unroll
        for (int q = 0; q < 7; ++q)
          *(float4*)&rr[q * 4] = *(const float4*)&simg[(y + ky) * 36 + q * 4];
#pragma unroll
        for (int kx = 0; kx < 9; ++kx) {
          const float w = wr[ky * 9 + kx];
#pragma unroll
          for (int ox = 0; ox < 20; ++ox) a20[ox] = fmaf(w, rr[ox + kx], a20[ox]);
        }
      }
      short* hp = &c1hi[(y * 20) * 36 + ci];
      short* lp = &c1lo[(y * 20) * 36 + ci];
#pragma unroll
      for (int x = 0; x < 20; ++x) {
        const float v = fmaxf(a20[x], 0.f);
        const short hi = f2bf(v);
        hp[x * 36] = hi;
        lp[x * 36] = f2bf(v - bf2f(hi));
      }
    }
    __syncthreads();
    // ---- phase B: 81 taps, K=32 (this ci chunk), 4-way split MFMA ----
    for (int ky = 0; ky < 9; ++ky) {
#pragma unroll
      for (int kx = 0; kx < 9; ++kx) {
        const int aofs = (ky * 20 + kx) * 36;
        s16x8 ah[3], al[3];
#pragma unroll
        for (int m = 0; m < 3; ++m) {
          const int ix = abase[m] + aofs;  // 8B-aligned -> b64 pairs
          s16x4 p = *(const s16x4*)&c1hi[ix];
          s16x4 q = *(const s16x4*)&c1hi[ix + 4];
          ah[m] = __builtin_shufflevector(p, q, 0, 1, 2, 3, 4, 5, 6, 7);
          p = *(const s16x4*)&c1lo[ix];
          q = *(const s16x4*)&c1lo[ix + 4];
          al[m] = __builtin_shufflevector(p, q, 0, 1, 2, 3, 4, 5, 6, 7);
        }
        const size_t tbase = (size_t)(ky * 9 + kx) * 65536 + chunk * 32;
        s16x8 bh[2], bl[2];
#pragma unroll
        for (int j = 0; j < 2; ++j) {
          bh[j] = *(const s16x8*)&whi[tbase + boff[j]];  // 16B aligned
          bl[j] = *(const s16x8*)&wlo[tbase + boff[j]];
        }
        // 4 split products, 6 independent acc chains interleaved
#pragma unroll
        for (int m = 0; m < 3; ++m)
#pragma unroll
          for (int j = 0; j < 2; ++j)
            acc[m][j] = __builtin_amdgcn_mfma_f32_16x16x32_bf16(ah[m], bh[j], acc[m][j], 0, 0, 0);
#pragma unroll
        for (int m = 0; m < 3; ++m)
#pragma unroll
          for (int j = 0; j < 2; ++j)
            acc[m][j] = __builtin_amdgcn_mfma_f32_16x16x32_bf16(al[m], bh[j], acc[m][j], 0, 0, 0);
#pragma unroll
        for (int m = 0; m < 3; ++m)
#pragma unroll
          for (int j = 0; j < 2; ++j)
            acc[m][j] = __builtin_amdgcn_mfma_f32_16x16x32_bf16(ah[m], bl[j], acc[m][j], 0, 0, 0);
#pragma unroll
        for (int m = 0; m < 3; ++m)
#pragma unroll
          for (int j = 0; j < 2; ++j)
            acc[m][j] = __builtin_amdgcn_mfma_f32_16x16x32_bf16(al[m], bl[j], acc[m][j], 0, 0, 0);
      }
    }
  }
  // ---- store: D col=lane&15, row=(lane>>4)*4+reg; xcaps[b][n][d] ----
#pragma unroll
  for (int m = 0; m < 3; ++m) {
#pragma unroll
    for (int jj = 0; jj < 4; ++jj) {
      const int pos = m * 16 + kg * 4 + jj;
      if (pos < 36) {
#pragma unroll
        for (int j = 0; j < 2; ++j) {
          const int co = con[j];
          const int n = (co & 31) * 36 + pos;
          xcaps[((size_t)b * 1152 + n) * 8 + (co >> 5)] = acc[m][j][jj] + bias[j];
        }
      }
    }
  }
}

// ---------------- fused u_hat + routing: block per (o,b) ----------------
__global__ __launch_bounds__(256) void routing_fused(const float* __restrict__ xcaps,
                                                     const float* __restrict__ W,
                                                     float* __restrict__ out) {
  const int o = blockIdx.x >> 8;
  const int b = blockIdx.x & 255;
  const int t = threadIdx.x;
  const int k = t & 15, ng = t >> 4;
  __shared__ float xs[1152 * 9];  // x[b] padded stride 8->9
  __shared__ double redA[256];
  __shared__ double redB[256];
  __shared__ float s_s[16];
  __shared__ float s_sv;
  __shared__ double s_f;

  {
    const float4* src = (const float4*)(xcaps + (size_t)b * 9216);
    for (int idx = t; idx < 2304; idx += 256) {
      float4 v = src[idx];
      const int n = idx >> 1, h = idx & 1;
      float* dst = &xs[n * 9 + h * 4];
      dst[0] = v.x; dst[1] = v.y; dst[2] = v.z; dst[3] = v.w;
    }
  }
  __syncthreads();

  const int n0 = ng * 72;
  float u[72];
  const float* wp = W + ((size_t)(n0 * 10 + o) * 16 + k) * 8;
#pragma unroll
  for (int i = 0; i < 72; ++i) {
    const float* wq = wp + (size_t)i * 1280;
    const float4 wa = *(const float4*)wq;
    const float4 wb = *(const float4*)(wq + 4);
    const float* xp = &xs[(n0 + i) * 9];
    float s = fmaf(wa.x, xp[0], 0.f);
    s = fmaf(wa.y, xp[1], s);
    s = fmaf(wa.z, xp[2], s);
    s = fmaf(wa.w, xp[3], s);
    s = fmaf(wb.x, xp[4], s);
    s = fmaf(wb.y, xp[5], s);
    s = fmaf(wb.z, xp[6], s);
    s = fmaf(wb.w, xp[7], s);
    u[i] = s;
  }

  // ---- pass 1: uniform c = 1/1152 ----
  double S = 0.0;
#pragma unroll
  for (int i = 0; i < 72; ++i) S += (double)u[i];
  redA[t] = S;
  __syncthreads();
  if (t < 16) {
    double tt = 0.0;
#pragma unroll
    for (int g = 0; g < 16; ++g) tt += redA[g * 16 + t];
    s_s[t] = (float)(tt * (double)(1.0f / 1152.0f));
  }
  __syncthreads();
  if (t == 0) {
    double sn = 0.0;
#pragma unroll
    for (int kk = 0; kk < 16; ++kk) sn += (double)s_s[kk] * (double)s_s[kk];
    const double f = sn / ((1.0 + sn) * sqrt(sn));
    double sv = 0.0;
#pragma unroll
    for (int kk = 0; kk < 16; ++kk) sv += (double)s_s[kk] * f;
    s_sv = (float)sv;
  }
  __syncthreads();
  const float sv1 = s_sv;

  // ---- pass 2: logits u*sv1 ----
  double E = 0.0, EU = 0.0;
#pragma unroll
  for (int i = 0; i < 72; ++i) {
    const float e = expf(u[i] * sv1);
    E += (double)e;
    EU += (double)e * (double)u[i];
  }
  redA[t] = E; redB[t] = EU;
  __syncthreads();
  if (t < 16) {
    double te = 0.0, tu = 0.0;
#pragma unroll
    for (int g = 0; g < 16; ++g) { te += redA[g * 16 + t]; tu += redB[g * 16 + t]; }
    s_s[t] = (float)(tu / te);
  }
  __syncthreads();
  if (t == 0) {
    double sn = 0.0;
#pragma unroll
    for (int kk = 0; kk < 16; ++kk) sn += (double)s_s[kk] * (double)s_s[kk];
    const double f = sn / ((1.0 + sn) * sqrt(sn));
    double sv = 0.0;
#pragma unroll
    for (int kk = 0; kk < 16; ++kk) sv += (double)s_s[kk] * f;
    s_sv = sv1 + (float)sv;
  }
  __syncthreads();
  const float sv12 = s_sv;

  // ---- pass 3 -> output ----
  E = 0.0; EU = 0.0;
#pragma unroll
  for (int i = 0; i < 72; ++i) {
    const float e = expf(u[i] * sv12);
    E += (double)e;
    EU += (double)e * (double)u[i];
  }
  redA[t] = E; redB[t] = EU;
  __syncthreads();
  if (t < 16) {
    double te = 0.0, tu = 0.0;
#pragma unroll
    for (int g = 0; g < 16; ++g) { te += redA[g * 16 + t]; tu += redB[g * 16 + t]; }
    s_s[t] = (float)(tu / te);
  }
  __syncthreads();
  if (t == 0) {
    double sn = 0.0;
#pragma unroll
    for (int kk = 0; kk < 16; ++kk) sn += (double)s_s[kk] * (double)s_s[kk];
    s_f = sn / ((1.0 + sn) * sqrt(sn));
  }
  __syncthreads();
  if (t < 16) out[b * 160 + o * 16 + t] = (float)((double)s_s[t] * s_f);
}

extern "C" void kernel_launch(void* const* d_in, const int* in_sizes, int n_in,
                              void* d_out, int out_size, void* d_ws, size_t ws_size,
                              hipStream_t stream) {
  const float* data = (const float*)d_in[0];
  const float* w1   = (const float*)d_in[1];
  const float* b1   = (const float*)d_in[2];
  const float* w2   = (const float*)d_in[3];
  const float* b2   = (const float*)d_in[4];
  const float* W    = (const float*)d_in[5];
  float* out = (float*)d_out;

  short* whi   = (short*)d_ws;           // 5,308,416 shorts
  short* wlo   = whi + 5308416;          // 5,308,416 shorts
  float* xcaps = (float*)(wlo + 5308416);// 2,359,296 floats (16B-aligned)

  prep_w2<<<256, 256, 0, stream>>>(w2, whi, wlo);
  conv2_mfma<<<512, 256, 0, stream>>>(data, w1, b1, whi, wlo, b2, xcaps);
  routing_fused<<<2560, 256, 0, stream>>>(xcaps, W, out);
}